// Round 2
// baseline (19179.907 us; speedup 1.0000x reference)
//
#include <hip/hip_runtime.h>

// LSTM_61203283968689 — fused 3-layer LSTM, f16-dot2, persistent per-block scan. R2.
// B=1024, T=512, IN=22, H=64. 256 blocks x 512 threads; 4 samples/block; 1 block/CU.
// Thread = (j in [0,64), s in [0,4), half in {0,1}); half0 -> gate rows {j, j+64} (i,f),
// half1 -> rows {j+128, j+192} (g,o). Partner exchange via shfl_xor(1) (same wave).
// R2 changes vs R1:
//  - __launch_bounds__(512,1): 256-VGPR budget -> no in-loop scratch spill
//    (R1: VGPR_Count=128, WRITE_SIZE=278MB of scratch traffic).
//  - Weight LDS: row stride 64 pairs (zero pad) + XOR swizzle phys = kk ^ ((2r)&63);
//    lane banks = kk ^ 2j' -> 8 banks x 2 addrs (half) = free 2-way; explicit b64 reads.
//  - Activation stride 98 pairs (banks 2s apart, broadcast-free).

#define BSZ 1024
#define TT 512
#define IN_DIM 22
#define HDIM 64
#define NG 256
#define GS 4
#define NTH 512

typedef _Float16 h16;
typedef __attribute__((ext_vector_type(2))) _Float16 h16x2;
typedef __attribute__((ext_vector_type(4))) _Float16 h16x4;

#if __has_builtin(__builtin_amdgcn_fdot2)
__device__ __forceinline__ float fdot2f(h16x2 a, h16x2 b, float c) {
    return __builtin_amdgcn_fdot2(a, b, c, false);
}
#else
__device__ __forceinline__ float fdot2f(h16x2 a, h16x2 b, float c) {
    return c + (float)a[0] * (float)b[0] + (float)a[1] * (float)b[1];
}
#endif

__device__ __forceinline__ h16x2 lo2(h16x4 v) { return __builtin_shufflevector(v, v, 0, 1); }
__device__ __forceinline__ h16x2 hi2(h16x4 v) { return __builtin_shufflevector(v, v, 2, 3); }

__device__ __forceinline__ float sigf(float z)   { return 1.f / (1.f + __expf(-z)); }
__device__ __forceinline__ float tanhf_(float z) { return 1.f - 2.f / (1.f + __expf(2.f * z)); }

__global__ __launch_bounds__(NTH, 1) void lstm_fused(
    const float* __restrict__ x,
    const float* __restrict__ wih0, const float* __restrict__ whh0,
    const float* __restrict__ bih0, const float* __restrict__ bhh0,
    const float* __restrict__ wih1, const float* __restrict__ whh1,
    const float* __restrict__ bih1, const float* __restrict__ bhh1,
    const float* __restrict__ wih2, const float* __restrict__ whh2,
    const float* __restrict__ bih2, const float* __restrict__ bhh2,
    const float* __restrict__ wfc, const float* __restrict__ bfc,
    float* __restrict__ out)
{
    const int tid  = threadIdx.x;
    const int half = tid & 1;
    const int s    = (tid >> 1) & 3;
    const int j    = tid >> 3;
    const int b4   = blockIdx.x * GS;

    // LDS: 2*65536 + 3136 + 192 + 1088 = 135,488 B
    __shared__ alignas(16) h16x2 WL1[NG * 64];
    __shared__ alignas(16) h16x2 WL2[NG * 64];
    __shared__ alignas(16) h16x2 HA[2][GS][98];  // per sample: h0[0..31], h1[32..63], h2[64..95]
    __shared__ alignas(16) h16x2 XA[GS][12];     // x_t, 11 pair-dwords used
    __shared__ float HF[GS][68];                 // final h2 in fp32 for FC

    const int r0 = j + 64 * (half * 2 + 0);
    const int r1 = j + 64 * (half * 2 + 1);
    const int e  = (2 * j) & 63;                 // XOR swizzle key (same for r0, r1)

    // ---- stage L1/L2 weights into LDS f16 pairs, XOR-swizzled within each row ----
    for (int idx = tid; idx < NG * 64; idx += NTH) {
        const int r = idx >> 6, kk = idx & 63;
        const int dst = r * 64 + (kk ^ ((2 * r) & 63));
        float a, b;
        h16x2 p;
        if (kk < 32) { a = wih1[r * 64 + 2 * kk];        b = wih1[r * 64 + 2 * kk + 1]; }
        else         { a = whh1[r * 64 + 2 * (kk - 32)]; b = whh1[r * 64 + 2 * (kk - 32) + 1]; }
        p[0] = (h16)a; p[1] = (h16)b;
        WL1[dst] = p;
        if (kk < 32) { a = wih2[r * 64 + 2 * kk];        b = wih2[r * 64 + 2 * kk + 1]; }
        else         { a = whh2[r * 64 + 2 * (kk - 32)]; b = whh2[r * 64 + 2 * (kk - 32) + 1]; }
        p[0] = (h16)a; p[1] = (h16)b;
        WL2[dst] = p;
    }

    // ---- L0 weights into registers: [x(22) | h0(64)] -> 43 pair-dwords per row ----
    h16x2 w0[2][43];
    #pragma unroll
    for (int mi = 0; mi < 2; ++mi) {
        const int r = j + 64 * (half * 2 + mi);
        #pragma unroll
        for (int kk = 0; kk < 11; ++kk) {
            h16x2 p;
            p[0] = (h16)wih0[r * IN_DIM + 2 * kk];
            p[1] = (h16)wih0[r * IN_DIM + 2 * kk + 1];
            w0[mi][kk] = p;
        }
        #pragma unroll
        for (int kk = 0; kk < 32; ++kk) {
            h16x2 p;
            p[0] = (h16)whh0[r * 64 + 2 * kk];
            p[1] = (h16)whh0[r * 64 + 2 * kk + 1];
            w0[mi][11 + kk] = p;
        }
    }

    // biases (b_ih + b_hh folded)
    float bs0[2], bs1[2], bs2[2];
    bs0[0] = bih0[r0] + bhh0[r0]; bs0[1] = bih0[r1] + bhh0[r1];
    bs1[0] = bih1[r0] + bhh1[r0]; bs1[1] = bih1[r1] + bhh1[r1];
    bs2[0] = bih2[r0] + bhh2[r0]; bs2[1] = bih2[r1] + bhh2[r1];

    // zero h ping-pong
    {
        h16x2 z; z[0] = (h16)0.f; z[1] = (h16)0.f;
        h16x2* hp = &HA[0][0][0];
        for (int idx = tid; idx < 2 * GS * 98; idx += NTH) hp[idx] = z;
    }
    // stage x_0
    if (tid < GS * IN_DIM) {
        const int ss = tid / IN_DIM, ii = tid % IN_DIM;
        ((h16*)&XA[ss][0])[ii] = (h16)x[(size_t)(b4 + ss) * (IN_DIM * TT) + ii * TT + 0];
    }
    float c0 = 0.f, c1 = 0.f, c2 = 0.f;
    float h2last = 0.f;
    __syncthreads();

    const h16x2* w1r0 = &WL1[r0 * 64];
    const h16x2* w1r1 = &WL1[r1 * 64];
    const h16x2* w2r0 = &WL2[r0 * 64];
    const h16x2* w2r1 = &WL2[r1 * 64];

    #pragma unroll 1
    for (int t = 0; t < TT; ++t) {
        const int op = t & 1, np = op ^ 1;
        const h16x2* hold  = &HA[op][s][0];
        const h16x2* hnew  = &HA[np][s][0];
        h16*         hnewh = (h16*)&HA[np][s][0];

        // ================= Layer 0 : gates = W0(regs) * [x_t ; h0_old] =================
        {
            float a0 = bs0[0], a1 = bs0[1], b0 = 0.f, b1 = 0.f;
            #pragma unroll
            for (int kk = 0; kk < 10; kk += 2) {
                h16x4 vq = *(const h16x4*)(&XA[s][kk]);
                a0 = fdot2f(w0[0][kk],     lo2(vq), a0);  a1 = fdot2f(w0[1][kk],     lo2(vq), a1);
                b0 = fdot2f(w0[0][kk + 1], hi2(vq), b0);  b1 = fdot2f(w0[1][kk + 1], hi2(vq), b1);
            }
            { h16x2 v = XA[s][10];
              a0 = fdot2f(w0[0][10], v, a0);  a1 = fdot2f(w0[1][10], v, a1); }
            #pragma unroll
            for (int kk = 0; kk < 32; kk += 2) {
                h16x4 vq = *(const h16x4*)(hold + kk);
                a0 = fdot2f(w0[0][11 + kk],     lo2(vq), a0);  a1 = fdot2f(w0[1][11 + kk],     lo2(vq), a1);
                b0 = fdot2f(w0[0][11 + kk + 1], hi2(vq), b0);  b1 = fdot2f(w0[1][11 + kk + 1], hi2(vq), b1);
            }
            a0 += b0; a1 += b1;
            const float pa0 = __shfl_xor(a0, 1);
            const float pa1 = __shfl_xor(a1, 1);
            if (half == 0) {
                const float ig = sigf(a0), fg = sigf(a1), gg = tanhf_(pa0), og = sigf(pa1);
                c0 = fg * c0 + ig * gg;
                hnewh[0 + j] = (h16)(og * tanhf_(c0));
            }
        }
        __syncthreads();

        // ============ Layer 1 : gates = W1 * [h0_new ; h1_old] ============
        {
            float a0 = bs1[0], a1 = bs1[1], b0 = 0.f, b1 = 0.f;
            #pragma unroll
            for (int kk = 0; kk < 32; kk += 2) {
                h16x4 wq0 = *(const h16x4*)(w1r0 + (kk ^ e));
                h16x4 wq1 = *(const h16x4*)(w1r1 + (kk ^ e));
                h16x4 vq  = *(const h16x4*)(hnew + kk);
                a0 = fdot2f(lo2(wq0), lo2(vq), a0);  a1 = fdot2f(lo2(wq1), lo2(vq), a1);
                b0 = fdot2f(hi2(wq0), hi2(vq), b0);  b1 = fdot2f(hi2(wq1), hi2(vq), b1);
            }
            #pragma unroll
            for (int kk = 32; kk < 64; kk += 2) {
                h16x4 wq0 = *(const h16x4*)(w1r0 + (kk ^ e));
                h16x4 wq1 = *(const h16x4*)(w1r1 + (kk ^ e));
                h16x4 vq  = *(const h16x4*)(hold + kk);
                a0 = fdot2f(lo2(wq0), lo2(vq), a0);  a1 = fdot2f(lo2(wq1), lo2(vq), a1);
                b0 = fdot2f(hi2(wq0), hi2(vq), b0);  b1 = fdot2f(hi2(wq1), hi2(vq), b1);
            }
            a0 += b0; a1 += b1;
            const float pa0 = __shfl_xor(a0, 1);
            const float pa1 = __shfl_xor(a1, 1);
            if (half == 0) {
                const float ig = sigf(a0), fg = sigf(a1), gg = tanhf_(pa0), og = sigf(pa1);
                c1 = fg * c1 + ig * gg;
                hnewh[64 + j] = (h16)(og * tanhf_(c1));
            }
        }
        __syncthreads();

        // ============ Layer 2 : gates = W2 * [h1_new ; h2_old] ============
        {
            float a0 = bs2[0], a1 = bs2[1], b0 = 0.f, b1 = 0.f;
            #pragma unroll
            for (int kk = 0; kk < 32; kk += 2) {
                h16x4 wq0 = *(const h16x4*)(w2r0 + (kk ^ e));
                h16x4 wq1 = *(const h16x4*)(w2r1 + (kk ^ e));
                h16x4 vq  = *(const h16x4*)(hnew + 32 + kk);
                a0 = fdot2f(lo2(wq0), lo2(vq), a0);  a1 = fdot2f(lo2(wq1), lo2(vq), a1);
                b0 = fdot2f(hi2(wq0), hi2(vq), b0);  b1 = fdot2f(hi2(wq1), hi2(vq), b1);
            }
            #pragma unroll
            for (int kk = 32; kk < 64; kk += 2) {
                h16x4 wq0 = *(const h16x4*)(w2r0 + (kk ^ e));
                h16x4 wq1 = *(const h16x4*)(w2r1 + (kk ^ e));
                h16x4 vq  = *(const h16x4*)(hold + 32 + kk);
                a0 = fdot2f(lo2(wq0), lo2(vq), a0);  a1 = fdot2f(lo2(wq1), lo2(vq), a1);
                b0 = fdot2f(hi2(wq0), hi2(vq), b0);  b1 = fdot2f(hi2(wq1), hi2(vq), b1);
            }
            a0 += b0; a1 += b1;

            // prefetch x_{t+1} into XA (consumed next step in L0; barrier below orders it)
            if (t + 1 < TT && tid < GS * IN_DIM) {
                const int ss = tid / IN_DIM, ii = tid % IN_DIM;
                ((h16*)&XA[ss][0])[ii] =
                    (h16)x[(size_t)(b4 + ss) * (IN_DIM * TT) + ii * TT + (t + 1)];
            }

            const float pa0 = __shfl_xor(a0, 1);
            const float pa1 = __shfl_xor(a1, 1);
            if (half == 0) {
                const float ig = sigf(a0), fg = sigf(a1), gg = tanhf_(pa0), og = sigf(pa1);
                c2 = fg * c2 + ig * gg;
                const float hv = og * tanhf_(c2);
                hnewh[128 + j] = (h16)hv;
                h2last = hv;
            }
        }
        __syncthreads();
    }

    // final h2 (fp32, from registers) -> FC
    if (half == 0) HF[s][j] = h2last;
    __syncthreads();

    if (tid < GS * 4) {
        const int ss = tid >> 2, o = tid & 3;
        float acc = bfc[o];
        #pragma unroll
        for (int jj = 0; jj < HDIM; ++jj) acc += HF[ss][jj] * wfc[o * HDIM + jj];
        out[(b4 + ss) * 4 + o] = acc;
    }
}

extern "C" void kernel_launch(void* const* d_in, const int* in_sizes, int n_in,
                              void* d_out, int out_size, void* d_ws, size_t ws_size,
                              hipStream_t stream) {
    const float* x    = (const float*)d_in[0];
    const float* wih0 = (const float*)d_in[1];
    const float* whh0 = (const float*)d_in[2];
    const float* bih0 = (const float*)d_in[3];
    const float* bhh0 = (const float*)d_in[4];
    const float* wih1 = (const float*)d_in[5];
    const float* whh1 = (const float*)d_in[6];
    const float* bih1 = (const float*)d_in[7];
    const float* bhh1 = (const float*)d_in[8];
    const float* wih2 = (const float*)d_in[9];
    const float* whh2 = (const float*)d_in[10];
    const float* bih2 = (const float*)d_in[11];
    const float* bhh2 = (const float*)d_in[12];
    const float* wfc  = (const float*)d_in[13];
    const float* bfc  = (const float*)d_in[14];
    float* out = (float*)d_out;

    lstm_fused<<<dim3(BSZ / GS), dim3(NTH), 0, stream>>>(
        x, wih0, whh0, bih0, bhh0, wih1, whh1, bih1, bhh1,
        wih2, whh2, bih2, bhh2, wfc, bfc, out);
}

// Round 3
// 1863.864 us; speedup vs baseline: 10.2904x; 10.2904x over previous
//
#include <hip/hip_runtime.h>

// LSTM_61203283968689 — R3: MFMA-based fused 3-layer LSTM.
// 64 blocks x 512 threads (8 waves); block owns 16 samples for all 512 steps.
// Gate rows reordered row' = 4*u + g  (u=hidden unit, g in {i,f,g,o}) so a 16-wide
// N-tile holds all 4 gates of 4 units -> elementwise via quad DPP, no LDS roundtrip.
// Weights: B-fragments in registers (11 chunks x 2 tiles x 4 VGPR = 88), loaded once.
// Activations: h[layer][pp][m][72] f16 in LDS, group-rotated so A-frag ds_read_b128
// is conflict-uniform; x transposed into LDS in 32-step double-buffered chunks.
// Per step: 22 MFMA(16x16x32 f16)/wave, 11 ds_read_b128/wave, 3 barriers.

#define TT  512
#define NTH 512

typedef _Float16 h16;
typedef __attribute__((ext_vector_type(8))) _Float16 h16x8;
typedef __attribute__((ext_vector_type(4))) float f32x4;

#define MFMA16(a, b, c) __builtin_amdgcn_mfma_f32_16x16x32_f16((a), (b), (c), 0, 0, 0)

__device__ __forceinline__ float dppx1(float v) {
    return __builtin_bit_cast(float, __builtin_amdgcn_mov_dpp(
        __builtin_bit_cast(int, v), 0xB1 /*quad_perm [1,0,3,2]*/, 0xF, 0xF, true));
}
__device__ __forceinline__ float dppx2(float v) {
    return __builtin_bit_cast(float, __builtin_amdgcn_mov_dpp(
        __builtin_bit_cast(int, v), 0x4E /*quad_perm [2,3,0,1]*/, 0xF, 0xF, true));
}

__device__ __forceinline__ float sigm(float z) {
    return __builtin_amdgcn_rcpf(1.f + __expf(-z));
}

// Load a B-fragment: 8 consecutive k of row `ro` from row-major W[.,ld], f32 -> f16.
__device__ __forceinline__ h16x8 loadB(const float* __restrict__ W, int ld, int ro,
                                       int k0, int kmax) {
    h16x8 r;
    #pragma unroll
    for (int i = 0; i < 8; ++i) {
        const int k = k0 + i;
        r[i] = (h16)((k < kmax) ? W[(size_t)ro * ld + k] : 0.f);
    }
    return r;
}

__global__ __attribute__((amdgpu_flat_work_group_size(NTH, NTH), amdgpu_waves_per_eu(2, 2)))
void lstm_mfma(
    const float* __restrict__ x,
    const float* __restrict__ wih0, const float* __restrict__ whh0,
    const float* __restrict__ bih0, const float* __restrict__ bhh0,
    const float* __restrict__ wih1, const float* __restrict__ whh1,
    const float* __restrict__ bih1, const float* __restrict__ bhh1,
    const float* __restrict__ wih2, const float* __restrict__ whh2,
    const float* __restrict__ bih2, const float* __restrict__ bhh2,
    const float* __restrict__ wfc, const float* __restrict__ bfc,
    float* __restrict__ out)
{
    const int tid  = threadIdx.x;
    const int w    = tid >> 6;        // wave 0..7 ; owns tiles {w, w+8}
    const int lane = tid & 63;
    const int nloc = lane & 15;       // B-frag col / A-frag row (m)
    const int kg   = lane >> 4;       // k-group 0..3
    const int b16  = blockIdx.x * 16;

    // LDS: XL 64 KiB + HT 13.5 KiB
    __shared__ alignas(16) h16 XL[2 * 32 * 16 * 32];  // [buf][t32][m16][k32]
    __shared__ alignas(16) h16 HT[3 * 2 * 16 * 72];   // [layer][pp][m16][72]

    // ---------------- B fragments (weights, registers, loaded once) --------------
    // chunks: 0: L0 x (wih0, k0=0, kmax 22)   1,2: L0 h0_old (whh0, k0 0/32)
    //         3,4: L1 h0_new (wih1)           5,6: L1 h1_old (whh1)
    //         7,8: L2 h1_new (wih2)           9,10: L2 h2_old (whh2)
    h16x8 Bf[2][11];
    float bias[3][2];
    #pragma unroll
    for (int s2 = 0; s2 < 2; ++s2) {
        const int col = (w + 8 * s2) * 16 + nloc;   // reordered gate-row index
        const int u = col >> 2, g = col & 3;
        const int ro = g * 64 + u;                  // original row (PyTorch i,f,g,o blocks)
        Bf[s2][0]  = loadB(wih0, 22, ro,  kg * 8,      22);
        Bf[s2][1]  = loadB(whh0, 64, ro,  kg * 8,      64);
        Bf[s2][2]  = loadB(whh0, 64, ro,  32 + kg * 8, 64);
        Bf[s2][3]  = loadB(wih1, 64, ro,  kg * 8,      64);
        Bf[s2][4]  = loadB(wih1, 64, ro,  32 + kg * 8, 64);
        Bf[s2][5]  = loadB(whh1, 64, ro,  kg * 8,      64);
        Bf[s2][6]  = loadB(whh1, 64, ro,  32 + kg * 8, 64);
        Bf[s2][7]  = loadB(wih2, 64, ro,  kg * 8,      64);
        Bf[s2][8]  = loadB(wih2, 64, ro,  32 + kg * 8, 64);
        Bf[s2][9]  = loadB(whh2, 64, ro,  kg * 8,      64);
        Bf[s2][10] = loadB(whh2, 64, ro,  32 + kg * 8, 64);
        bias[0][s2] = bih0[ro] + bhh0[ro];
        bias[1][s2] = bih1[ro] + bhh1[ro];
        bias[2][s2] = bih2[ro] + bhh2[ro];
    }

    // ---------------- zero LDS ----------------
    {
        int* xz = (int*)XL;
        for (int i = tid; i < 2 * 32 * 16 * 16; i += NTH) xz[i] = 0;
        int* hz = (int*)HT;
        for (int i = tid; i < 3 * 2 * 16 * 36; i += NTH) hz[i] = 0;
    }
    __syncthreads();

    // ---------------- x staging: chunk -> XL[buf][t][m][k] (transposed) ----------
    auto stage_x = [&](int chunk) {
        if (tid < 16 * 22) {
            const int bl = tid / 22, ii = tid - bl * 22;
            const float* src = x + (size_t)(b16 + bl) * (22 * 512) + (size_t)ii * 512
                                 + chunk * 32;
            h16* dst = &XL[(size_t)((chunk & 1) * 32) * 512 + bl * 32 + ii];
            #pragma unroll
            for (int q = 0; q < 8; ++q) {
                const float4 v = ((const float4*)src)[q];
                dst[(q * 4 + 0) * 512] = (h16)v.x;
                dst[(q * 4 + 1) * 512] = (h16)v.y;
                dst[(q * 4 + 2) * 512] = (h16)v.z;
                dst[(q * 4 + 3) * 512] = (h16)v.w;
            }
        }
    };
    stage_x(0);

    // ---------------- per-lane constant offsets ----------------
    const int m = nloc;  // A-frag row = sample
    // A-frag offsets into a 16x72 h16 activation buffer (group-rotation swizzle):
    // logical group = 4*chalf + kg ; physical group = (logical + 3m) & 7
    const int aoff0 = m * 72 + (((kg)     + 3 * m) & 7) * 8;  // k in [0,32)
    const int aoff1 = m * 72 + (((4 + kg) + 3 * m) & 7) * 8;  // k in [32,64)
    // h-write offsets (writer lanes nloc%4==0): C-row m_w = kg*4 + r
    int woff[2][4];
    const int ul = nloc >> 2;
    #pragma unroll
    for (int s2 = 0; s2 < 2; ++s2) {
        const int u = 4 * (w + 8 * s2) + ul;
        #pragma unroll
        for (int r = 0; r < 4; ++r) {
            const int mw = kg * 4 + r;
            woff[s2][r] = mw * 72 + ((((u >> 3) + 3 * mw) & 7) * 8) + (u & 7);
        }
    }
    const bool wr  = ((nloc & 3) == 0);
    const bool isG = ((nloc & 3) == 2);
    const bool p1  = (nloc & 1) != 0;
    const bool p2  = (nloc & 2) != 0;

    f32x4 c0[2] = {{0,0,0,0},{0,0,0,0}};
    f32x4 c1[2] = {{0,0,0,0},{0,0,0,0}};
    f32x4 c2[2] = {{0,0,0,0},{0,0,0,0}};

    // elementwise: activate own gate, quad-DPP butterfly, select by p, update c, emit h
    auto ew = [&](f32x4 z, f32x4& cst, h16* hb, const int* wo) {
        float hv[4];
        #pragma unroll
        for (int r = 0; r < 4; ++r) {
            const float zz = isG ? z[r] + z[r] : z[r];
            const float s  = sigm(zz);
            const float v  = isG ? 2.f * s - 1.f : s;
            const float w1 = dppx1(v), w2 = dppx2(v), w3 = dppx2(w1);
            const float A0 = p1 ? w1 : v,  A1 = p1 ? v : w1;
            const float A2 = p1 ? w3 : w2, A3 = p1 ? w2 : w3;
            const float gi = p2 ? A2 : A0, gf = p2 ? A3 : A1;
            const float gg = p2 ? A0 : A2, go = p2 ? A1 : A3;
            const float c = gf * cst[r] + gi * gg;
            cst[r] = c;
            hv[r] = go * (2.f * sigm(2.f * c) - 1.f);
        }
        if (wr) {
            #pragma unroll
            for (int r = 0; r < 4; ++r) hb[wo[r]] = (h16)hv[r];
        }
    };

    __syncthreads();

    #pragma unroll 1
    for (int t = 0; t < TT; ++t) {
        const int op = t & 1, np = op ^ 1;
        const h16* h0o = HT + (0 * 2 + op) * 1152;
        h16*       h0n = HT + (0 * 2 + np) * 1152;
        const h16* h1o = HT + (2 + op) * 1152;
        h16*       h1n = HT + (2 + np) * 1152;
        const h16* h2o = HT + (4 + op) * 1152;
        h16*       h2n = HT + (4 + np) * 1152;
        const int  xix = (((t >> 5) & 1) * 32 + (t & 31)) * 512 + m * 32 + kg * 8;

        // ---------- Layer 0: gates = Wx*x_t + Wh*h0_old ----------
        {
            f32x4 z0 = {bias[0][0], bias[0][0], bias[0][0], bias[0][0]};
            f32x4 z1 = {bias[0][1], bias[0][1], bias[0][1], bias[0][1]};
            h16x8 a;
            a = *(const h16x8*)&XL[xix];
            z0 = MFMA16(a, Bf[0][0], z0);  z1 = MFMA16(a, Bf[1][0], z1);
            a = *(const h16x8*)(h0o + aoff0);
            z0 = MFMA16(a, Bf[0][1], z0);  z1 = MFMA16(a, Bf[1][1], z1);
            a = *(const h16x8*)(h0o + aoff1);
            z0 = MFMA16(a, Bf[0][2], z0);  z1 = MFMA16(a, Bf[1][2], z1);
            ew(z0, c0[0], h0n, woff[0]);
            ew(z1, c0[1], h0n, woff[1]);
        }
        __syncthreads();

        // ---------- Layer 1: gates = Wih1*h0_new + Whh1*h1_old ----------
        {
            f32x4 z0 = {bias[1][0], bias[1][0], bias[1][0], bias[1][0]};
            f32x4 z1 = {bias[1][1], bias[1][1], bias[1][1], bias[1][1]};
            h16x8 a;
            a = *(const h16x8*)(h0n + aoff0);
            z0 = MFMA16(a, Bf[0][3], z0);  z1 = MFMA16(a, Bf[1][3], z1);
            a = *(const h16x8*)(h0n + aoff1);
            z0 = MFMA16(a, Bf[0][4], z0);  z1 = MFMA16(a, Bf[1][4], z1);
            a = *(const h16x8*)(h1o + aoff0);
            z0 = MFMA16(a, Bf[0][5], z0);  z1 = MFMA16(a, Bf[1][5], z1);
            a = *(const h16x8*)(h1o + aoff1);
            z0 = MFMA16(a, Bf[0][6], z0);  z1 = MFMA16(a, Bf[1][6], z1);
            ew(z0, c1[0], h1n, woff[0]);
            ew(z1, c1[1], h1n, woff[1]);
        }
        __syncthreads();

        // ---------- Layer 2: gates = Wih2*h1_new + Whh2*h2_old ----------
        {
            f32x4 z0 = {bias[2][0], bias[2][0], bias[2][0], bias[2][0]};
            f32x4 z1 = {bias[2][1], bias[2][1], bias[2][1], bias[2][1]};
            h16x8 a;
            a = *(const h16x8*)(h1n + aoff0);
            z0 = MFMA16(a, Bf[0][7], z0);  z1 = MFMA16(a, Bf[1][7], z1);
            a = *(const h16x8*)(h1n + aoff1);
            z0 = MFMA16(a, Bf[0][8], z0);  z1 = MFMA16(a, Bf[1][8], z1);
            a = *(const h16x8*)(h2o + aoff0);
            z0 = MFMA16(a, Bf[0][9], z0);  z1 = MFMA16(a, Bf[1][9], z1);
            a = *(const h16x8*)(h2o + aoff1);
            z0 = MFMA16(a, Bf[0][10], z0); z1 = MFMA16(a, Bf[1][10], z1);

            // refresh next x chunk mid-window (consumed after >=1 barrier)
            if ((t & 31) == 16 && (t >> 5) + 1 < 16) stage_x((t >> 5) + 1);

            ew(z0, c2[0], h2n, woff[0]);
            ew(z1, c2[1], h2n, woff[1]);
        }
        __syncthreads();
    }

    // ---------------- FC epilogue: out = h2_final @ wfc^T + bfc ----------------
    if (tid < 64) {
        const int ms = tid >> 2, o = tid & 3;
        const h16* h2 = HT + 4 * 1152 + ms * 72;  // np at t=511 is 0
        float acc = bfc[o];
        #pragma unroll 1
        for (int p = 0; p < 64; ++p) {
            const int u = ((((p >> 3) - 3 * ms) & 7) << 3) | (p & 7);
            acc += (float)h2[p] * wfc[o * 64 + u];
        }
        out[(b16 + ms) * 4 + o] = acc;
    }
}

extern "C" void kernel_launch(void* const* d_in, const int* in_sizes, int n_in,
                              void* d_out, int out_size, void* d_ws, size_t ws_size,
                              hipStream_t stream) {
    const float* x    = (const float*)d_in[0];
    const float* wih0 = (const float*)d_in[1];
    const float* whh0 = (const float*)d_in[2];
    const float* bih0 = (const float*)d_in[3];
    const float* bhh0 = (const float*)d_in[4];
    const float* wih1 = (const float*)d_in[5];
    const float* whh1 = (const float*)d_in[6];
    const float* bih1 = (const float*)d_in[7];
    const float* bhh1 = (const float*)d_in[8];
    const float* wih2 = (const float*)d_in[9];
    const float* whh2 = (const float*)d_in[10];
    const float* bih2 = (const float*)d_in[11];
    const float* bhh2 = (const float*)d_in[12];
    const float* wfc  = (const float*)d_in[13];
    const float* bfc  = (const float*)d_in[14];
    float* out = (float*)d_out;

    lstm_mfma<<<dim3(64), dim3(NTH), 0, stream>>>(
        x, wih0, whh0, bih0, bhh0, wih1, whh1, bih1, bhh1,
        wih2, whh2, bih2, bhh2, wfc, bfc, out);
}

// Round 4
// 1562.120 us; speedup vs baseline: 12.2781x; 1.1932x over previous
//
#include <hip/hip_runtime.h>

// LSTM_61203283968689 — R4: MFMA fused 3-layer LSTM, diagonal layer pipeline.
// 64 blocks x 512 threads (8 waves); block owns 16 samples for all 512 steps.
// Tick t computes: L0(time t), L1(time t-1), L2(time t-2). All activation reads
// come from the buffer written BEFORE the last barrier -> ONE barrier per tick,
// 3 independent chains per wave, 7 shared ds_read_b128 per wave per tick.
// Activation LDS layout is fragment-linear: lane reads at lane*16B (+1024B for
// k-high chunk) -> conflict-free. h element [m][u] at (u>>3)*128 + m*8 + (u&7).
// Gate columns interleaved col=4u+g; elementwise via 4 quad-broadcast DPPs.

#define TT  512
#define NTH 512

typedef _Float16 h16;
typedef __attribute__((ext_vector_type(8))) _Float16 h16x8;
typedef __attribute__((ext_vector_type(4))) float f32x4;

#define MFMA16(a, b, c) __builtin_amdgcn_mfma_f32_16x16x32_f16((a), (b), (c), 0, 0, 0)

__device__ __forceinline__ float dppb(float v, int pat) {
    switch (pat) {
    case 0: return __builtin_bit_cast(float, __builtin_amdgcn_mov_dpp(
        __builtin_bit_cast(int, v), 0x00, 0xF, 0xF, true));
    case 1: return __builtin_bit_cast(float, __builtin_amdgcn_mov_dpp(
        __builtin_bit_cast(int, v), 0x55, 0xF, 0xF, true));
    case 2: return __builtin_bit_cast(float, __builtin_amdgcn_mov_dpp(
        __builtin_bit_cast(int, v), 0xAA, 0xF, 0xF, true));
    default: return __builtin_bit_cast(float, __builtin_amdgcn_mov_dpp(
        __builtin_bit_cast(int, v), 0xFF, 0xF, 0xF, true));
    }
}

__device__ __forceinline__ float sigm(float z) {
    return __builtin_amdgcn_rcpf(1.f + __expf(-z));
}

// B-fragment: 8 consecutive k of row `ro` from row-major W[.,ld], f32 -> f16.
__device__ __forceinline__ h16x8 loadB(const float* __restrict__ W, int ld, int ro,
                                       int k0, int kmax) {
    h16x8 r;
    #pragma unroll
    for (int i = 0; i < 8; ++i) {
        const int k = k0 + i;
        r[i] = (h16)((k < kmax) ? W[(size_t)ro * ld + k] : 0.f);
    }
    return r;
}

__global__ __attribute__((amdgpu_flat_work_group_size(NTH, NTH), amdgpu_waves_per_eu(2, 2)))
void lstm_mfma(
    const float* __restrict__ x,
    const float* __restrict__ wih0, const float* __restrict__ whh0,
    const float* __restrict__ bih0, const float* __restrict__ bhh0,
    const float* __restrict__ wih1, const float* __restrict__ whh1,
    const float* __restrict__ bih1, const float* __restrict__ bhh1,
    const float* __restrict__ wih2, const float* __restrict__ whh2,
    const float* __restrict__ bih2, const float* __restrict__ bhh2,
    const float* __restrict__ wfc, const float* __restrict__ bfc,
    float* __restrict__ out)
{
    const int tid  = threadIdx.x;
    const int w    = tid >> 6;        // wave 0..7 ; owns gate-tiles {w, w+8}
    const int lane = tid & 63;
    const int nloc = lane & 15;       // A-frag row m / B-frag col
    const int kg   = lane >> 4;       // k-group 0..3
    const int b16  = blockIdx.x * 16;

    // LDS: XL 64 KiB (x, 2 chunks x 32 t x 512 h16) + HT 12 KiB (3 layers x 2 bufs x 1024)
    __shared__ alignas(16) h16 XL[2 * 32 * 512];
    __shared__ alignas(16) h16 HT[3 * 2 * 1024];

    // ---------------- B fragments (weights, registers, loaded once) --------------
    h16x8 Bf[2][11];
    float bias[3][2];
    #pragma unroll
    for (int s2 = 0; s2 < 2; ++s2) {
        const int col = (w + 8 * s2) * 16 + nloc;   // interleaved gate-row index
        const int u = col >> 2, g = col & 3;
        const int ro = g * 64 + u;                  // original row (i,f,g,o blocks)
        Bf[s2][0]  = loadB(wih0, 22, ro,  kg * 8,      22);
        Bf[s2][1]  = loadB(whh0, 64, ro,  kg * 8,      64);
        Bf[s2][2]  = loadB(whh0, 64, ro,  32 + kg * 8, 64);
        Bf[s2][3]  = loadB(wih1, 64, ro,  kg * 8,      64);
        Bf[s2][4]  = loadB(wih1, 64, ro,  32 + kg * 8, 64);
        Bf[s2][5]  = loadB(whh1, 64, ro,  kg * 8,      64);
        Bf[s2][6]  = loadB(whh1, 64, ro,  32 + kg * 8, 64);
        Bf[s2][7]  = loadB(wih2, 64, ro,  kg * 8,      64);
        Bf[s2][8]  = loadB(wih2, 64, ro,  32 + kg * 8, 64);
        Bf[s2][9]  = loadB(whh2, 64, ro,  kg * 8,      64);
        Bf[s2][10] = loadB(whh2, 64, ro,  32 + kg * 8, 64);
        bias[0][s2] = bih0[ro] + bhh0[ro];
        bias[1][s2] = bih1[ro] + bhh1[ro];
        bias[2][s2] = bih2[ro] + bhh2[ro];
    }

    // ---------------- zero LDS (x pad lanes must stay zero) ----------------
    {
        int* xz = (int*)XL;
        for (int i = tid; i < 2 * 32 * 256; i += NTH) xz[i] = 0;
        int* hz = (int*)HT;
        for (int i = tid; i < 3 * 2 * 512; i += NTH) hz[i] = 0;
    }
    __syncthreads();

    // ---------------- x staging: chunk -> XL, fragment-order [i>>3][m][i&7] ------
    auto stage_x = [&](int chunk) {
        if (tid < 16 * 22) {
            const int bl = tid / 22, ii = tid - bl * 22;
            const float* src = x + (size_t)(b16 + bl) * (22 * 512) + (size_t)ii * 512
                                 + chunk * 32;
            h16* dst = &XL[(chunk & 1) * (32 * 512) + (ii >> 3) * 128 + bl * 8 + (ii & 7)];
            #pragma unroll
            for (int q = 0; q < 8; ++q) {
                const float4 v = ((const float4*)src)[q];
                dst[(q * 4 + 0) * 512] = (h16)v.x;
                dst[(q * 4 + 1) * 512] = (h16)v.y;
                dst[(q * 4 + 2) * 512] = (h16)v.z;
                dst[(q * 4 + 3) * 512] = (h16)v.w;
            }
        }
    };
    stage_x(0);

    // ---------------- per-lane constants ----------------
    const int  lo8 = lane * 8;            // A-frag k-low offset (h16 units)
    const bool wr  = ((nloc & 3) == 0);
    const bool isG = ((nloc & 3) == 2);
    int wbase[2];
    #pragma unroll
    for (int s2 = 0; s2 < 2; ++s2) {
        const int u = 4 * (w + 8 * s2) + (nloc >> 2);
        wbase[s2] = (u >> 3) * 128 + kg * 32 + (u & 7);   // + r*8 per row
    }

    f32x4 c0[2] = {{0,0,0,0},{0,0,0,0}};
    f32x4 c1[2] = {{0,0,0,0},{0,0,0,0}};
    f32x4 c2[2] = {{0,0,0,0},{0,0,0,0}};

    // elementwise: activate own gate, quad-broadcast 4 gates, update c, emit h
    auto ew = [&](f32x4 z, f32x4& cst, h16* hb, int wb_) {
        #pragma unroll
        for (int r = 0; r < 4; ++r) {
            const float zz = isG ? z[r] + z[r] : z[r];
            const float sv = sigm(zz);
            const float v  = isG ? 2.f * sv - 1.f : sv;
            const float gi = dppb(v, 0);
            const float gf = dppb(v, 1);
            const float gg = dppb(v, 2);
            const float go = dppb(v, 3);
            const float c  = gf * cst[r] + gi * gg;
            cst[r] = c;
            const float hv = go * (2.f * sigm(2.f * c) - 1.f);
            if (wr) hb[wb_ + r * 8] = (h16)hv;
        }
    };

    __syncthreads();

    // ============================ diagonal tick loop ============================
    #pragma unroll 1
    for (int t = 0; t < TT + 2; ++t) {
        const int wb = t & 1, rb = wb ^ 1;
        const h16* h0r = HT + 0 * 2048 + rb * 1024;
        h16*       h0w = HT + 0 * 2048 + wb * 1024;
        const h16* h1r = HT + 1 * 2048 + rb * 1024;
        h16*       h1w = HT + 1 * 2048 + wb * 1024;
        const h16* h2r = HT + 2 * 2048 + rb * 1024;
        h16*       h2w = HT + 2 * 2048 + wb * 1024;

        // shared fragment loads (each buffer read exactly once per wave)
        const h16x8 ax   = *(const h16x8*)&XL[((t >> 5) & 1) * (32 * 512)
                                              + (t & 31) * 512 + lo8];
        const h16x8 a0lo = *(const h16x8*)(h0r + lo8);
        const h16x8 a0hi = *(const h16x8*)(h0r + lo8 + 512);
        const h16x8 a1lo = *(const h16x8*)(h1r + lo8);
        const h16x8 a1hi = *(const h16x8*)(h1r + lo8 + 512);
        const h16x8 a2lo = *(const h16x8*)(h2r + lo8);
        const h16x8 a2hi = *(const h16x8*)(h2r + lo8 + 512);

        if (t < TT) {            // -------- L0 (time t): x(t), h0(t-1) --------
            f32x4 z0 = {bias[0][0], bias[0][0], bias[0][0], bias[0][0]};
            f32x4 z1 = {bias[0][1], bias[0][1], bias[0][1], bias[0][1]};
            z0 = MFMA16(ax,   Bf[0][0], z0);  z1 = MFMA16(ax,   Bf[1][0], z1);
            z0 = MFMA16(a0lo, Bf[0][1], z0);  z1 = MFMA16(a0lo, Bf[1][1], z1);
            z0 = MFMA16(a0hi, Bf[0][2], z0);  z1 = MFMA16(a0hi, Bf[1][2], z1);
            ew(z0, c0[0], h0w, wbase[0]);
            ew(z1, c0[1], h0w, wbase[1]);
        }
        if (t >= 1 && t < TT + 1) {  // ---- L1 (time t-1): h0(t-1), h1(t-2) ----
            f32x4 z0 = {bias[1][0], bias[1][0], bias[1][0], bias[1][0]};
            f32x4 z1 = {bias[1][1], bias[1][1], bias[1][1], bias[1][1]};
            z0 = MFMA16(a0lo, Bf[0][3], z0);  z1 = MFMA16(a0lo, Bf[1][3], z1);
            z0 = MFMA16(a0hi, Bf[0][4], z0);  z1 = MFMA16(a0hi, Bf[1][4], z1);
            z0 = MFMA16(a1lo, Bf[0][5], z0);  z1 = MFMA16(a1lo, Bf[1][5], z1);
            z0 = MFMA16(a1hi, Bf[0][6], z0);  z1 = MFMA16(a1hi, Bf[1][6], z1);
            ew(z0, c1[0], h1w, wbase[0]);
            ew(z1, c1[1], h1w, wbase[1]);
        }
        if (t >= 2) {            // ------ L2 (time t-2): h1(t-2), h2(t-3) ------
            f32x4 z0 = {bias[2][0], bias[2][0], bias[2][0], bias[2][0]};
            f32x4 z1 = {bias[2][1], bias[2][1], bias[2][1], bias[2][1]};
            z0 = MFMA16(a1lo, Bf[0][7],  z0);  z1 = MFMA16(a1lo, Bf[1][7],  z1);
            z0 = MFMA16(a1hi, Bf[0][8],  z0);  z1 = MFMA16(a1hi, Bf[1][8],  z1);
            z0 = MFMA16(a2lo, Bf[0][9],  z0);  z1 = MFMA16(a2lo, Bf[1][9],  z1);
            z0 = MFMA16(a2hi, Bf[0][10], z0);  z1 = MFMA16(a2hi, Bf[1][10], z1);
            ew(z0, c2[0], h2w, wbase[0]);
            ew(z1, c2[1], h2w, wbase[1]);
        }

        // stage next x chunk mid-window (visible after this tick's barrier)
        if ((t & 31) == 16 && (t >> 5) < 15) stage_x((t >> 5) + 1);

        __syncthreads();
    }

    // ---------------- FC epilogue: h2(time 511) is in buffer (513&1)=1 -----------
    if (tid < 64) {
        const int ms = tid >> 2, o = tid & 3;
        const h16* h2 = HT + 2 * 2048 + 1024;
        float acc = bfc[o];
        #pragma unroll 1
        for (int u = 0; u < 64; ++u)
            acc += (float)h2[(u >> 3) * 128 + ms * 8 + (u & 7)] * wfc[o * 64 + u];
        out[(b16 + ms) * 4 + o] = acc;
    }
}

extern "C" void kernel_launch(void* const* d_in, const int* in_sizes, int n_in,
                              void* d_out, int out_size, void* d_ws, size_t ws_size,
                              hipStream_t stream) {
    const float* x    = (const float*)d_in[0];
    const float* wih0 = (const float*)d_in[1];
    const float* whh0 = (const float*)d_in[2];
    const float* bih0 = (const float*)d_in[3];
    const float* bhh0 = (const float*)d_in[4];
    const float* wih1 = (const float*)d_in[5];
    const float* whh1 = (const float*)d_in[6];
    const float* bih1 = (const float*)d_in[7];
    const float* bhh1 = (const float*)d_in[8];
    const float* wih2 = (const float*)d_in[9];
    const float* whh2 = (const float*)d_in[10];
    const float* bih2 = (const float*)d_in[11];
    const float* bhh2 = (const float*)d_in[12];
    const float* wfc  = (const float*)d_in[13];
    const float* bfc  = (const float*)d_in[14];
    float* out = (float*)d_out;

    lstm_mfma<<<dim3(64), dim3(NTH), 0, stream>>>(
        x, wih0, whh0, bih0, bhh0, wih1, whh1, bih1, bhh1,
        wih2, whh2, bih2, bhh2, wfc, bfc, out);
}

// Round 5
// 525.170 us; speedup vs baseline: 36.5213x; 2.9745x over previous
//
#include <hip/hip_runtime.h>

// LSTM_61203283968689 — R5: MFMA fused 3-layer LSTM, diagonal pipeline, all-CU.
// 256 blocks x 256 threads (4 waves); block owns 4 samples, mapped to MFMA C-rows
// {0,4,8,12} (= register r=0 for kg=0..3) -> elementwise touches ONE register row
// with ZERO wasted lanes. Gate-BLOCKED tiles: wave w owns 4 N-tiles = gates
// {i,f,g,o} of units [16w,16w+16) -> zi/zf/zg/zo all in-lane: no DPP, no
// redundant tanh. 10 transcendentals per (unit,sample) = intrinsic minimum.
// Diagonal tick t: L0(t), L1(t-1), L2(t-2); ONE barrier/tick; 7 ds_read_b128/wave.
// Weights as B-fragments in VGPRs (4 gates x 11 chunks = 176 VGPR, waves_per_eu(1)
// unlocks 512). LDS pad forces 1 block/CU.

#define TT   512
#define NTH  256
#define NBLK 256

typedef _Float16 h16;
typedef __attribute__((ext_vector_type(8))) _Float16 h16x8;
typedef __attribute__((ext_vector_type(4))) float f32x4;

#define MFMA16(a, b, c) __builtin_amdgcn_mfma_f32_16x16x32_f16((a), (b), (c), 0, 0, 0)

__device__ __forceinline__ float sigm(float z) {
    return __builtin_amdgcn_rcpf(1.f + __expf(-z));
}

// B-fragment: 8 consecutive k of row `ro` from row-major W[.,ld], f32 -> f16.
__device__ __forceinline__ h16x8 loadB(const float* __restrict__ W, int ld, int ro,
                                       int k0, int kmax) {
    h16x8 r;
    #pragma unroll
    for (int i = 0; i < 8; ++i) {
        const int k = k0 + i;
        r[i] = (h16)((k < kmax) ? W[(size_t)ro * ld + k] : 0.f);
    }
    return r;
}

__global__ __attribute__((amdgpu_flat_work_group_size(NTH, NTH), amdgpu_waves_per_eu(1)))
void lstm_mfma(
    const float* __restrict__ x,
    const float* __restrict__ wih0, const float* __restrict__ whh0,
    const float* __restrict__ bih0, const float* __restrict__ bhh0,
    const float* __restrict__ wih1, const float* __restrict__ whh1,
    const float* __restrict__ bih1, const float* __restrict__ bhh1,
    const float* __restrict__ wih2, const float* __restrict__ whh2,
    const float* __restrict__ bih2, const float* __restrict__ bhh2,
    const float* __restrict__ wfc, const float* __restrict__ bfc,
    float* __restrict__ out)
{
    const int tid  = threadIdx.x;
    const int w    = tid >> 6;        // wave 0..3 ; owns gates {i,f,g,o} of units [16w,16w+16)
    const int lane = tid & 63;
    const int nloc = lane & 15;       // unit-local index / A-frag col pos
    const int kg   = lane >> 4;       // k-group 0..3 ; ALSO the sample index (row 4*kg)
    const int b4   = blockIdx.x * 4;
    const int u    = w * 16 + nloc;   // this lane's hidden unit

    // LDS: XL 64 KiB + HT 12 KiB + PAD 6 KiB = 84 KiB -> exactly 1 block/CU
    __shared__ alignas(16) h16 XL[2 * 32 * 512];   // x, 2 chunks x 32 t x frag-tile(512)
    __shared__ alignas(16) h16 HT[3 * 2 * 1024];   // h[layer][pp] frag-tiles
    __shared__ h16 PAD[3072];                      // occupancy limiter (kept alive below)

    // ---------------- B fragments: Bf[gate][chunk], loaded once ----------------
    // chunks: 0: L0 x (wih0, kmax 22)   1,2: L0 h0_old (whh0, k0 0/32)
    //         3,4: L1 h0_new (wih1)     5,6: L1 h1_old (whh1)
    //         7,8: L2 h1_new (wih2)     9,10: L2 h2_old (whh2)
    h16x8 Bf[4][11];
    float bias[3][4];
    #pragma unroll
    for (int g = 0; g < 4; ++g) {
        const int ro = g * 64 + u;                  // original row (i,f,g,o blocks)
        Bf[g][0]  = loadB(wih0, 22, ro,  kg * 8,      22);
        Bf[g][1]  = loadB(whh0, 64, ro,  kg * 8,      64);
        Bf[g][2]  = loadB(whh0, 64, ro,  32 + kg * 8, 64);
        Bf[g][3]  = loadB(wih1, 64, ro,  kg * 8,      64);
        Bf[g][4]  = loadB(wih1, 64, ro,  32 + kg * 8, 64);
        Bf[g][5]  = loadB(whh1, 64, ro,  kg * 8,      64);
        Bf[g][6]  = loadB(whh1, 64, ro,  32 + kg * 8, 64);
        Bf[g][7]  = loadB(wih2, 64, ro,  kg * 8,      64);
        Bf[g][8]  = loadB(wih2, 64, ro,  32 + kg * 8, 64);
        Bf[g][9]  = loadB(whh2, 64, ro,  kg * 8,      64);
        Bf[g][10] = loadB(whh2, 64, ro,  32 + kg * 8, 64);
        bias[0][g] = bih0[ro] + bhh0[ro];
        bias[1][g] = bih1[ro] + bhh1[ro];
        bias[2][g] = bih2[ro] + bhh2[ro];
    }

    // keep PAD alive (condition can never be true at runtime)
    if (bias[0][0] > 1.0e30f) { PAD[tid] = (h16)bias[0][0]; out[0] = (float)PAD[0]; }

    // ---------------- zero LDS (pad rows must stay zero) ----------------
    {
        int* xz = (int*)XL;
        for (int i = tid; i < 2 * 32 * 256; i += NTH) xz[i] = 0;
        int* hz = (int*)HT;
        for (int i = tid; i < 3 * 2 * 512; i += NTH) hz[i] = 0;
    }
    __syncthreads();

    // ---------------- x staging: sample bl -> A-row 4*bl, frag layout ------------
    // frag element (m, k) at (k>>3)*128 + m*8 + (k&7) within a 512-slab per t.
    auto stage_x = [&](int chunk) {
        if (tid < 4 * 22) {
            const int bl = tid / 22, ii = tid - bl * 22;
            const float* src = x + (size_t)(b4 + bl) * (22 * 512) + (size_t)ii * 512
                                 + chunk * 32;
            h16* dst = &XL[(chunk & 1) * (32 * 512) + (ii >> 3) * 128 + (4 * bl) * 8 + (ii & 7)];
            #pragma unroll
            for (int q = 0; q < 8; ++q) {
                const float4 v = ((const float4*)src)[q];
                dst[(q * 4 + 0) * 512] = (h16)v.x;
                dst[(q * 4 + 1) * 512] = (h16)v.y;
                dst[(q * 4 + 2) * 512] = (h16)v.z;
                dst[(q * 4 + 3) * 512] = (h16)v.w;
            }
        }
    };
    stage_x(0);

    // ---------------- per-lane constants ----------------
    const int lo8  = lane * 8;                           // A-frag offset (h16 units)
    const int hoff = (u >> 3) * 128 + kg * 32 + (u & 7); // h-write: row 4*kg, unit u

    float c0 = 0.f, c1 = 0.f, c2 = 0.f;

    // elementwise: 4 gates in-lane, update c, emit h. 10 trans per call.
    auto ew = [&](const f32x4& zi, const f32x4& zf, const f32x4& zg, const f32x4& zo,
                  float& cst, h16* hb) {
        const float vi = sigm(zi[0]);
        const float vf = sigm(zf[0]);
        const float vg = 2.f * sigm(2.f * zg[0]) - 1.f;
        const float vo = sigm(zo[0]);
        const float c  = vf * cst + vi * vg;
        cst = c;
        hb[hoff] = (h16)(vo * (2.f * sigm(2.f * c) - 1.f));
    };

    __syncthreads();

    // ============================ diagonal tick loop ============================
    #pragma unroll 1
    for (int t = 0; t < TT + 2; ++t) {
        const int wb = t & 1, rb = wb ^ 1;
        const h16* h0r = HT + 0 * 2048 + rb * 1024;
        h16*       h0w = HT + 0 * 2048 + wb * 1024;
        const h16* h1r = HT + 1 * 2048 + rb * 1024;
        h16*       h1w = HT + 1 * 2048 + wb * 1024;
        const h16* h2r = HT + 2 * 2048 + rb * 1024;
        h16*       h2w = HT + 2 * 2048 + wb * 1024;

        // shared fragment loads (each buffer read exactly once per wave)
        const h16x8 ax   = *(const h16x8*)&XL[((t >> 5) & 1) * (32 * 512)
                                              + (t & 31) * 512 + lo8];
        const h16x8 a0lo = *(const h16x8*)(h0r + lo8);
        const h16x8 a0hi = *(const h16x8*)(h0r + lo8 + 512);
        const h16x8 a1lo = *(const h16x8*)(h1r + lo8);
        const h16x8 a1hi = *(const h16x8*)(h1r + lo8 + 512);
        const h16x8 a2lo = *(const h16x8*)(h2r + lo8);
        const h16x8 a2hi = *(const h16x8*)(h2r + lo8 + 512);

        if (t < TT) {            // -------- L0 (time t): x(t), h0(t-1) --------
            f32x4 z[4];
            #pragma unroll
            for (int g = 0; g < 4; ++g) {
                z[g] = f32x4{bias[0][g], 0.f, 0.f, 0.f};
                z[g] = MFMA16(ax,   Bf[g][0], z[g]);
                z[g] = MFMA16(a0lo, Bf[g][1], z[g]);
                z[g] = MFMA16(a0hi, Bf[g][2], z[g]);
            }
            ew(z[0], z[1], z[2], z[3], c0, h0w);
        }
        if (t >= 1 && t < TT + 1) {  // ---- L1 (time t-1): h0(t-1), h1(t-2) ----
            f32x4 z[4];
            #pragma unroll
            for (int g = 0; g < 4; ++g) {
                z[g] = f32x4{bias[1][g], 0.f, 0.f, 0.f};
                z[g] = MFMA16(a0lo, Bf[g][3], z[g]);
                z[g] = MFMA16(a0hi, Bf[g][4], z[g]);
                z[g] = MFMA16(a1lo, Bf[g][5], z[g]);
                z[g] = MFMA16(a1hi, Bf[g][6], z[g]);
            }
            ew(z[0], z[1], z[2], z[3], c1, h1w);
        }
        if (t >= 2) {            // ------ L2 (time t-2): h1(t-2), h2(t-3) ------
            f32x4 z[4];
            #pragma unroll
            for (int g = 0; g < 4; ++g) {
                z[g] = f32x4{bias[2][g], 0.f, 0.f, 0.f};
                z[g] = MFMA16(a1lo, Bf[g][7],  z[g]);
                z[g] = MFMA16(a1hi, Bf[g][8],  z[g]);
                z[g] = MFMA16(a2lo, Bf[g][9],  z[g]);
                z[g] = MFMA16(a2hi, Bf[g][10], z[g]);
            }
            ew(z[0], z[1], z[2], z[3], c2, h2w);
        }

        // stage next x chunk mid-window (visible after this tick's barrier)
        if ((t & 31) == 16 && (t >> 5) < 15) stage_x((t >> 5) + 1);

        __syncthreads();
    }

    // ------------- FC epilogue: h2(time 511) is in buffer (TT+1)&1 = 1 -----------
    if (tid < 16) {
        const int ms = tid >> 2, o = tid & 3;
        const h16* h2 = HT + 2 * 2048 + 1024;
        float acc = bfc[o];
        #pragma unroll 1
        for (int uu = 0; uu < 64; ++uu)
            acc += (float)h2[(uu >> 3) * 128 + (4 * ms) * 8 + (uu & 7)] * wfc[o * 64 + uu];
        out[(b4 + ms) * 4 + o] = acc;
    }
}

extern "C" void kernel_launch(void* const* d_in, const int* in_sizes, int n_in,
                              void* d_out, int out_size, void* d_ws, size_t ws_size,
                              hipStream_t stream) {
    const float* x    = (const float*)d_in[0];
    const float* wih0 = (const float*)d_in[1];
    const float* whh0 = (const float*)d_in[2];
    const float* bih0 = (const float*)d_in[3];
    const float* bhh0 = (const float*)d_in[4];
    const float* wih1 = (const float*)d_in[5];
    const float* whh1 = (const float*)d_in[6];
    const float* bih1 = (const float*)d_in[7];
    const float* bhh1 = (const float*)d_in[8];
    const float* wih2 = (const float*)d_in[9];
    const float* whh2 = (const float*)d_in[10];
    const float* bih2 = (const float*)d_in[11];
    const float* bhh2 = (const float*)d_in[12];
    const float* wfc  = (const float*)d_in[13];
    const float* bfc  = (const float*)d_in[14];
    float* out = (float*)d_out;

    lstm_mfma<<<dim3(NBLK), dim3(NTH), 0, stream>>>(
        x, wih0, whh0, bih0, bhh0, wih1, whh1, bih1, bhh1,
        wih2, whh2, bih2, bhh2, wfc, bfc, out);
}

// Round 6
// 421.485 us; speedup vs baseline: 45.5055x; 1.2460x over previous
//
#include <hip/hip_runtime.h>

// LSTM_61203283968689 — R6: MFMA fused 3-layer LSTM, diagonal pipeline,
// LAYER-SPECIALIZED wave groups. 256 blocks x 768 threads (12 waves):
// waves 0-3 -> L0(t), 4-7 -> L1(t-1), 8-11 -> L2(t-2). 3 waves/SIMD so one
// wave's MFMA exec overlaps another's transcendental chain (R5 had 1 wave/SIMD
// and ~55% dependency stall). Within a wave group, wave wg owns gates {i,f,g,o}
// of units [16wg,16wg+16) (gate-blocked tiles; all 4 gates in-lane, no DPP).
// Block owns 4 samples mapped to MFMA C-rows {0,4,8,12} (reg r=0 for kg=0..3).
// ONE barrier/tick. Weights as B-fragments in VGPRs (<=16 frags/wave).
// Activation LDS layout fragment-linear: lane reads at lane*16B, conflict-free.

#define TT   512
#define NTH  768
#define NBLK 256

typedef _Float16 h16;
typedef __attribute__((ext_vector_type(8))) _Float16 h16x8;
typedef __attribute__((ext_vector_type(4))) float f32x4;

#define MFMA16(a, b, c) __builtin_amdgcn_mfma_f32_16x16x32_f16((a), (b), (c), 0, 0, 0)

__device__ __forceinline__ float sigm(float z) {
    return __builtin_amdgcn_rcpf(1.f + __expf(-z));
}

// B-fragment: 8 consecutive k of row `ro` from row-major W[.,ld], f32 -> f16.
__device__ __forceinline__ h16x8 loadB(const float* __restrict__ W, int ld, int ro,
                                       int k0, int kmax) {
    h16x8 r;
    #pragma unroll
    for (int i = 0; i < 8; ++i) {
        const int k = k0 + i;
        r[i] = (h16)((k < kmax) ? W[(size_t)ro * ld + k] : 0.f);
    }
    return r;
}

__global__ __attribute__((amdgpu_flat_work_group_size(NTH, NTH), amdgpu_waves_per_eu(3)))
void lstm_mfma(
    const float* __restrict__ x,
    const float* __restrict__ wih0, const float* __restrict__ whh0,
    const float* __restrict__ bih0, const float* __restrict__ bhh0,
    const float* __restrict__ wih1, const float* __restrict__ whh1,
    const float* __restrict__ bih1, const float* __restrict__ bhh1,
    const float* __restrict__ wih2, const float* __restrict__ whh2,
    const float* __restrict__ bih2, const float* __restrict__ bhh2,
    const float* __restrict__ wfc, const float* __restrict__ bfc,
    float* __restrict__ out)
{
    const int tid  = threadIdx.x;
    const int w    = tid >> 6;        // wave 0..11
    const int wl   = w >> 2;          // layer 0..2
    const int wg   = w & 3;           // gate-tile group: units [16wg, 16wg+16)
    const int lane = tid & 63;
    const int nloc = lane & 15;       // unit-local index / B-frag col
    const int kg   = lane >> 4;       // k-group 0..3 ; also sample (C-row 4*kg)
    const int b4   = blockIdx.x * 4;
    const int u    = wg * 16 + nloc;  // this lane's hidden unit

    // LDS: XL 64 KiB + HT 12 KiB + PAD 6 KiB = 82 KiB -> exactly 1 block/CU
    __shared__ alignas(16) h16 XL[2 * 32 * 512];   // x, 2 chunks x 32 t x frag-tile(512)
    __shared__ alignas(16) h16 HT[3 * 2 * 1024];   // h[layer][pp] frag-tiles
    __shared__ h16 PAD[3072];                      // occupancy limiter (kept alive below)

    // ---------------- B fragments for THIS wave's layer only ----------------
    // L0: {x(wih0), h0lo(whh0), h0hi(whh0)}  L1: {h0lo,h0hi(wih1), h1lo,h1hi(whh1)}
    // L2: {h1lo,h1hi(wih2), h2lo,h2hi(whh2)}
    h16x8 Bf[4][4];
    float bias[4];
    #pragma unroll
    for (int g = 0; g < 4; ++g) {
        const int ro = g * 64 + u;                  // original row (i,f,g,o blocks)
        if (wl == 0) {
            Bf[g][0] = loadB(wih0, 22, ro, kg * 8,      22);
            Bf[g][1] = loadB(whh0, 64, ro, kg * 8,      64);
            Bf[g][2] = loadB(whh0, 64, ro, 32 + kg * 8, 64);
            Bf[g][3] = Bf[g][2];
            bias[g]  = bih0[ro] + bhh0[ro];
        } else if (wl == 1) {
            Bf[g][0] = loadB(wih1, 64, ro, kg * 8,      64);
            Bf[g][1] = loadB(wih1, 64, ro, 32 + kg * 8, 64);
            Bf[g][2] = loadB(whh1, 64, ro, kg * 8,      64);
            Bf[g][3] = loadB(whh1, 64, ro, 32 + kg * 8, 64);
            bias[g]  = bih1[ro] + bhh1[ro];
        } else {
            Bf[g][0] = loadB(wih2, 64, ro, kg * 8,      64);
            Bf[g][1] = loadB(wih2, 64, ro, 32 + kg * 8, 64);
            Bf[g][2] = loadB(whh2, 64, ro, kg * 8,      64);
            Bf[g][3] = loadB(whh2, 64, ro, 32 + kg * 8, 64);
            bias[g]  = bih2[ro] + bhh2[ro];
        }
    }

    // keep PAD alive (condition can never be true at runtime)
    if (bias[0] > 1.0e30f) { PAD[tid & 2047] = (h16)bias[0]; out[0] = (float)PAD[0]; }

    // ---------------- zero LDS (pad rows must stay zero) ----------------
    {
        int* xz = (int*)XL;
        for (int i = tid; i < 2 * 32 * 256; i += NTH) xz[i] = 0;
        int* hz = (int*)HT;
        for (int i = tid; i < 3 * 2 * 512; i += NTH) hz[i] = 0;
    }
    __syncthreads();

    // ---------------- x staging: sample bl -> A-row 4*bl, frag layout ------------
    // frag element (m, k) at (k>>3)*128 + m*8 + (k&7) within a 512-slab per t.
    // tid < 88 -> waves 0..1 (L0 group, which has the lightest MFMA load).
    auto stage_x = [&](int chunk) {
        if (tid < 4 * 22) {
            const int bl = tid / 22, ii = tid - bl * 22;
            const float* src = x + (size_t)(b4 + bl) * (22 * 512) + (size_t)ii * 512
                                 + chunk * 32;
            h16* dst = &XL[(chunk & 1) * (32 * 512) + (ii >> 3) * 128 + (4 * bl) * 8 + (ii & 7)];
            #pragma unroll
            for (int q = 0; q < 8; ++q) {
                const float4 v = ((const float4*)src)[q];
                dst[(q * 4 + 0) * 512] = (h16)v.x;
                dst[(q * 4 + 1) * 512] = (h16)v.y;
                dst[(q * 4 + 2) * 512] = (h16)v.z;
                dst[(q * 4 + 3) * 512] = (h16)v.w;
            }
        }
    };
    stage_x(0);

    // ---------------- per-lane constants ----------------
    const int lo8  = lane * 8;                           // A-frag offset (h16 units)
    const int hoff = (u >> 3) * 128 + kg * 32 + (u & 7); // h-write: row 4*kg, unit u

    float cst = 0.f;

    // elementwise: 4 gates in-lane, update c, emit h. 10 trans per call.
    auto ew = [&](const f32x4& zi, const f32x4& zf, const f32x4& zg, const f32x4& zo,
                  h16* hb) {
        const float vi = sigm(zi[0]);
        const float vf = sigm(zf[0]);
        const float vg = 2.f * sigm(2.f * zg[0]) - 1.f;
        const float vo = sigm(zo[0]);
        const float c  = vf * cst + vi * vg;
        cst = c;
        hb[hoff] = (h16)(vo * (2.f * sigm(2.f * c) - 1.f));
    };

    __syncthreads();

    // ============================ diagonal tick loop ============================
    #pragma unroll 1
    for (int t = 0; t < TT + 2; ++t) {
        const int wb = t & 1, rb = wb ^ 1;
        const h16* h0r = HT + 0 * 2048 + rb * 1024;
        h16*       h0w = HT + 0 * 2048 + wb * 1024;
        const h16* h1r = HT + 1 * 2048 + rb * 1024;
        h16*       h1w = HT + 1 * 2048 + wb * 1024;
        const h16* h2r = HT + 2 * 2048 + rb * 1024;
        h16*       h2w = HT + 2 * 2048 + wb * 1024;

        if (wl == 0) {           // -------- L0 (time t): x(t), h0(t-1) --------
            if (t < TT) {
                const h16x8 ax   = *(const h16x8*)&XL[((t >> 5) & 1) * (32 * 512)
                                                      + (t & 31) * 512 + lo8];
                const h16x8 a0lo = *(const h16x8*)(h0r + lo8);
                const h16x8 a0hi = *(const h16x8*)(h0r + lo8 + 512);
                f32x4 z[4];
                #pragma unroll
                for (int g = 0; g < 4; ++g) {
                    z[g] = f32x4{bias[g], 0.f, 0.f, 0.f};
                    z[g] = MFMA16(ax,   Bf[g][0], z[g]);
                    z[g] = MFMA16(a0lo, Bf[g][1], z[g]);
                    z[g] = MFMA16(a0hi, Bf[g][2], z[g]);
                }
                ew(z[0], z[1], z[2], z[3], h0w);
            }
            // stage next x chunk mid-window (visible after this tick's barrier)
            if ((t & 31) == 16 && (t >> 5) < 15) stage_x((t >> 5) + 1);
        } else if (wl == 1) {    // ---- L1 (time t-1): h0(t-1), h1(t-2) ----
            if (t >= 1 && t < TT + 1) {
                const h16x8 a0lo = *(const h16x8*)(h0r + lo8);
                const h16x8 a0hi = *(const h16x8*)(h0r + lo8 + 512);
                const h16x8 a1lo = *(const h16x8*)(h1r + lo8);
                const h16x8 a1hi = *(const h16x8*)(h1r + lo8 + 512);
                f32x4 z[4];
                #pragma unroll
                for (int g = 0; g < 4; ++g) {
                    z[g] = f32x4{bias[g], 0.f, 0.f, 0.f};
                    z[g] = MFMA16(a0lo, Bf[g][0], z[g]);
                    z[g] = MFMA16(a0hi, Bf[g][1], z[g]);
                    z[g] = MFMA16(a1lo, Bf[g][2], z[g]);
                    z[g] = MFMA16(a1hi, Bf[g][3], z[g]);
                }
                ew(z[0], z[1], z[2], z[3], h1w);
            }
        } else {                 // ------ L2 (time t-2): h1(t-2), h2(t-3) ------
            if (t >= 2) {
                const h16x8 a1lo = *(const h16x8*)(h1r + lo8);
                const h16x8 a1hi = *(const h16x8*)(h1r + lo8 + 512);
                const h16x8 a2lo = *(const h16x8*)(h2r + lo8);
                const h16x8 a2hi = *(const h16x8*)(h2r + lo8 + 512);
                f32x4 z[4];
                #pragma unroll
                for (int g = 0; g < 4; ++g) {
                    z[g] = f32x4{bias[g], 0.f, 0.f, 0.f};
                    z[g] = MFMA16(a1lo, Bf[g][0], z[g]);
                    z[g] = MFMA16(a1hi, Bf[g][1], z[g]);
                    z[g] = MFMA16(a2lo, Bf[g][2], z[g]);
                    z[g] = MFMA16(a2hi, Bf[g][3], z[g]);
                }
                ew(z[0], z[1], z[2], z[3], h2w);
            }
        }

        __syncthreads();
    }

    // ------------- FC epilogue: h2(time 511) is in buffer (TT+1)&1 = 1 -----------
    if (tid < 16) {
        const int ms = tid >> 2, o = tid & 3;
        const h16* h2 = HT + 2 * 2048 + 1024;
        float acc = bfc[o];
        #pragma unroll 1
        for (int uu = 0; uu < 64; ++uu)
            acc += (float)h2[(uu >> 3) * 128 + (4 * ms) * 8 + (uu & 7)] * wfc[o * 64 + uu];
        out[(b4 + ms) * 4 + o] = acc;
    }
}

extern "C" void kernel_launch(void* const* d_in, const int* in_sizes, int n_in,
                              void* d_out, int out_size, void* d_ws, size_t ws_size,
                              hipStream_t stream) {
    const float* x    = (const float*)d_in[0];
    const float* wih0 = (const float*)d_in[1];
    const float* whh0 = (const float*)d_in[2];
    const float* bih0 = (const float*)d_in[3];
    const float* bhh0 = (const float*)d_in[4];
    const float* wih1 = (const float*)d_in[5];
    const float* whh1 = (const float*)d_in[6];
    const float* bih1 = (const float*)d_in[7];
    const float* bhh1 = (const float*)d_in[8];
    const float* wih2 = (const float*)d_in[9];
    const float* whh2 = (const float*)d_in[10];
    const float* bih2 = (const float*)d_in[11];
    const float* bhh2 = (const float*)d_in[12];
    const float* wfc  = (const float*)d_in[13];
    const float* bfc  = (const float*)d_in[14];
    float* out = (float*)d_out;

    lstm_mfma<<<dim3(NBLK), dim3(NTH), 0, stream>>>(
        x, wih0, whh0, bih0, bhh0, wih1, whh1, bih1, bhh1,
        wih2, whh2, bih2, bhh2, wfc, bfc, out);
}